// Round 6
// baseline (3902.045 us; speedup 1.0000x reference)
//
#include <hip/hip_runtime.h>
#include <hip/hip_bf16.h>

typedef unsigned int uint32;
typedef unsigned short ushort16;

#define N_MATN 100000
#define N_ELEMN 118
#define F_MATN 128
#define F_ELEMN 64
#define HIDN 128
#define NHEAD 8
#define OUTC 64
#define SCORE_BLOCKS 1024
#define NT 8                      // nodes per tile
#define NTILES (N_MATN/NT)        // 12500 exactly

__device__ __forceinline__ float blo(uint32 u){ return __uint_as_float(u << 16); }
__device__ __forceinline__ float bhi(uint32 u){ return __uint_as_float(u & 0xffff0000u); }
__device__ __forceinline__ ushort16 f2bf(float f){
    uint32 u = __float_as_uint(f);
    uint32 r = u + 0x7FFFu + ((u >> 16) & 1u);   // RNE
    return (ushort16)(r >> 16);
}
__device__ __forceinline__ uint32 pack2(float a, float b){
    return (uint32)f2bf(a) | ((uint32)f2bf(b) << 16);
}

// ---------------- projection: elem nodes — one block per node
__global__ __launch_bounds__(128) void proj_elem_v2(
    const float* __restrict__ x, const float* __restrict__ W,
    const float* __restrict__ bias, const float* __restrict__ a_se,
    ushort16* __restrict__ h, float* __restrict__ asrc_em)
{
    __shared__ float xr[F_ELEMN];
    int n = blockIdx.x, c = threadIdx.x;
    if(c < 16) ((float4*)xr)[c] = ((const float4*)(x + n*F_ELEMN))[c];
    __syncthreads();
    const float4* Wr = (const float4*)(W + c*F_ELEMN);
    float acc = 0.f;
    #pragma unroll
    for(int i=0;i<16;i++){
        float4 w = Wr[i];
        acc += xr[4*i]*w.x + xr[4*i+1]*w.y + xr[4*i+2]*w.z + xr[4*i+3]*w.w;
    }
    acc += bias[c];
    h[n*HIDN + c] = f2bf(acc);
    float p = acc * a_se[c];
    #pragma unroll
    for(int m=8;m>=1;m>>=1) p += __shfl_xor(p, m, 16);
    if((c&15)==0) asrc_em[n*NHEAD + (c>>4)] = p;
}

// ---------------- projection: mat nodes — LDS-tiled, 8-node ILP, bf16 W in LDS
__global__ __launch_bounds__(128) void proj_mat_v2(
    const float* __restrict__ x, const float* __restrict__ W,
    const float* __restrict__ bias,
    const float* __restrict__ a_de, const float* __restrict__ a_sm, const float* __restrict__ a_dm,
    ushort16* __restrict__ h,
    float* __restrict__ adst_em, float* __restrict__ asrc_mm, float* __restrict__ adst_mm)
{
    __shared__ uint32 wlds[128*65];       // bf16-packed W, row stride 65 uints (bank-conflict-free)
    __shared__ float  xlds[NT*128];
    int t = threadIdx.x;
    {   // stage W row t as bf16 pairs
        const float4* Wr = (const float4*)(W + t*F_MATN);
        uint32* wrow_s = wlds + t*65;
        #pragma unroll
        for(int i=0;i<32;i++){
            float4 v = Wr[i];
            wrow_s[2*i]   = pack2(v.x, v.y);
            wrow_s[2*i+1] = pack2(v.z, v.w);
        }
    }
    float bc = bias[t];
    float ade = a_de[t], asm_ = a_sm[t], adm = a_dm[t];
    int hh = t >> 4;
    const uint32* wrow = wlds + t*65;
    __syncthreads();
    for(int tile = blockIdx.x; tile < NTILES; tile += gridDim.x){
        int n0 = tile*NT;
        __syncthreads();      // previous tile's xlds readers done
        {   // stage x tile: 8 nodes x 128 f32 = 256 float4
            const float4* xs = (const float4*)(x + (size_t)n0*F_MATN);
            float4 v0 = xs[t], v1 = xs[t+128];
            ((float4*)xlds)[t] = v0;
            ((float4*)xlds)[t+128] = v1;
        }
        __syncthreads();
        float acc[NT];
        #pragma unroll
        for(int n=0;n<NT;n++) acc[n] = 0.f;
        #pragma unroll
        for(int kk=0;kk<64;kk+=4){        // 4 uints = 8 k per chunk
            uint32 w0=wrow[kk], w1=wrow[kk+1], w2=wrow[kk+2], w3=wrow[kk+3];
            float f0=blo(w0),f1=bhi(w0),f2=blo(w1),f3=bhi(w1);
            float f4=blo(w2),f5=bhi(w2),f6=blo(w3),f7=bhi(w3);
            #pragma unroll
            for(int n=0;n<NT;n++){
                const float* xp = xlds + n*128 + kk*2;    // broadcast reads
                acc[n] += xp[0]*f0 + xp[1]*f1 + xp[2]*f2 + xp[3]*f3
                        + xp[4]*f4 + xp[5]*f5 + xp[6]*f6 + xp[7]*f7;
            }
        }
        #pragma unroll
        for(int n=0;n<NT;n++){
            float a = acc[n] + bc;
            h[(size_t)(n0+n)*HIDN + t] = f2bf(a);
            float p0 = a*ade, p1 = a*asm_, p2 = a*adm;
            #pragma unroll
            for(int m=8;m>=1;m>>=1){
                p0 += __shfl_xor(p0, m, 16);
                p1 += __shfl_xor(p1, m, 16);
                p2 += __shfl_xor(p2, m, 16);
            }
            if((t&15)==0){
                adst_em[(n0+n)*NHEAD+hh]=p0;
                asrc_mm[(n0+n)*NHEAD+hh]=p1;
                adst_mm[(n0+n)*NHEAD+hh]=p2;
            }
        }
    }
}

// ---------------- CSR build (unchanged from passing r5)
__global__ __launch_bounds__(256) void count_kernel(
    const int* __restrict__ dst, int nE, int* __restrict__ deg)
{
    int i = blockIdx.x*blockDim.x + threadIdx.x;
    int st = gridDim.x*blockDim.x;
    for(; i < nE; i += st) atomicAdd(&deg[dst[i]], 1);
}

__global__ __launch_bounds__(256) void scan_kernel(
    const int* __restrict__ deg, int* __restrict__ offs)
{
    __shared__ int part[256];
    int t = threadIdx.x;
    const int CH = (N_MATN + 255) >> 8;
    int beg = t*CH;
    int end = beg + CH; if(end > N_MATN) end = N_MATN;
    int s = 0;
    for(int i = beg; i < end; i++) s += deg[i];
    part[t] = s;
    __syncthreads();
    if(t == 0){
        int run = 0;
        for(int i = 0; i < 256; i++){ int v = part[i]; part[i] = run; run += v; }
    }
    __syncthreads();
    int run = part[t];
    for(int i = beg; i < end; i++){ offs[i] = run; run += deg[i]; }
    if(t == 255) offs[N_MATN] = run;
}

__global__ __launch_bounds__(256) void copy_kernel(
    const int* __restrict__ a, int* __restrict__ b, int n)
{
    int i = blockIdx.x*blockDim.x + threadIdx.x;
    int st = gridDim.x*blockDim.x;
    for(; i < n; i += st) b[i] = a[i];
}

__global__ __launch_bounds__(256) void scatter_kernel(
    const int* __restrict__ src, const int* __restrict__ dst, int nE,
    int* __restrict__ cur, int* __restrict__ csr)
{
    int i = blockIdx.x*blockDim.x + threadIdx.x;
    int st = gridDim.x*blockDim.x;
    for(; i < nE; i += st){
        int d = dst[i];
        int p = atomicAdd(&cur[d], 1);
        csr[p] = src[i];
    }
}

// ---------------- aggregation (unchanged from passing r5)
__global__ __launch_bounds__(256) void agg_kernel(
    const int* __restrict__ offs, const int* __restrict__ csr,
    const ushort16* __restrict__ hsrc, const float* __restrict__ asrc,
    const float* __restrict__ adst, ushort16* __restrict__ o)
{
    int lane = threadIdx.x & 63;
    int w = (blockIdx.x*blockDim.x + threadIdx.x) >> 6;
    int nw = (gridDim.x*blockDim.x) >> 6;
    int hh = lane >> 3;
    for(int d = w; d < N_MATN; d += nw){
        int beg = offs[d], end = offs[d+1];
        float ad = adst[d*NHEAD + hh];
        float den = 0.f, n0 = 0.f, n1 = 0.f;
        for(int j = beg; j < end; j++){
            int s = csr[j];
            float al = asrc[s*NHEAD + hh] + ad;
            al = al > 0.f ? al : 0.2f*al;
            float ex = __expf(al);
            den += ex;
            uint32 hv = ((const uint32*)hsrc)[s*64 + lane];
            n0 += blo(hv)*ex;
            n1 += bhi(hv)*ex;
        }
        float rdn = 1.0f/(den + 1e-16f);
        uint32 pk = (uint32)f2bf(fmaxf(n0*rdn, 0.f)) | ((uint32)f2bf(fmaxf(n1*rdn, 0.f)) << 16);
        ((uint32*)o)[(size_t)d*64 + lane] = pk;
    }
}

// ---------------- semantic scores — LDS-tiled
__global__ __launch_bounds__(128) void score_v2(
    const ushort16* __restrict__ o_em, const ushort16* __restrict__ o_mm,
    const float* __restrict__ Wk, const float* __restrict__ bkv,
    const float* __restrict__ qv, float* __restrict__ partials)
{
    __shared__ uint32 wlds[128*65];
    __shared__ uint32 xe[NT*64], xm[NT*64];
    int t = threadIdx.x;
    {
        const float4* Wr = (const float4*)(Wk + t*HIDN);
        uint32* wrow_s = wlds + t*65;
        #pragma unroll
        for(int i=0;i<32;i++){
            float4 v = Wr[i];
            wrow_s[2*i]   = pack2(v.x, v.y);
            wrow_s[2*i+1] = pack2(v.z, v.w);
        }
    }
    float bc = bkv[t], qc = qv[t];
    const uint32* wrow = wlds + t*65;
    float se = 0.f, sm = 0.f;
    __syncthreads();
    for(int tile = blockIdx.x; tile < NTILES; tile += gridDim.x){
        int n0 = tile*NT;
        __syncthreads();
        {   // stage o tiles: 8 nodes x 64 uints each = 128 uint4 per matrix
            const uint4* pe = (const uint4*)((const uint32*)o_em + (size_t)n0*64);
            const uint4* pm = (const uint4*)((const uint32*)o_mm + (size_t)n0*64);
            ((uint4*)xe)[t] = pe[t];
            ((uint4*)xm)[t] = pm[t];
        }
        __syncthreads();
        float ae[NT], am[NT];
        #pragma unroll
        for(int n=0;n<NT;n++){ ae[n]=0.f; am[n]=0.f; }
        #pragma unroll
        for(int kk=0;kk<64;kk+=4){
            uint32 w0=wrow[kk], w1=wrow[kk+1], w2=wrow[kk+2], w3=wrow[kk+3];
            float f0=blo(w0),f1=bhi(w0),f2=blo(w1),f3=bhi(w1);
            float f4=blo(w2),f5=bhi(w2),f6=blo(w3),f7=bhi(w3);
            #pragma unroll
            for(int n=0;n<NT;n++){
                uint4 e = *(const uint4*)(xe + n*64 + kk);
                ae[n] += blo(e.x)*f0 + bhi(e.x)*f1 + blo(e.y)*f2 + bhi(e.y)*f3
                       + blo(e.z)*f4 + bhi(e.z)*f5 + blo(e.w)*f6 + bhi(e.w)*f7;
                uint4 m = *(const uint4*)(xm + n*64 + kk);
                am[n] += blo(m.x)*f0 + bhi(m.x)*f1 + blo(m.y)*f2 + bhi(m.y)*f3
                       + blo(m.z)*f4 + bhi(m.z)*f5 + blo(m.w)*f6 + bhi(m.w)*f7;
            }
        }
        #pragma unroll
        for(int n=0;n<NT;n++){
            se += qc * tanhf(ae[n] + bc);
            sm += qc * tanhf(am[n] + bc);
        }
    }
    #pragma unroll
    for(int m=32;m>=1;m>>=1){ se += __shfl_xor(se,m); sm += __shfl_xor(sm,m); }
    __shared__ float red[4];
    int wv = t >> 6, ln = t & 63;
    if(ln==0){ red[wv*2]=se; red[wv*2+1]=sm; }
    __syncthreads();
    if(t==0){
        partials[blockIdx.x*2+0] = red[0]+red[2];
        partials[blockIdx.x*2+1] = red[1]+red[3];
    }
}

__global__ __launch_bounds__(256) void reduce_scores_kernel(
    const float* __restrict__ partials, float* __restrict__ scores)
{
    __shared__ float sh0[256], sh1[256];
    int t = threadIdx.x;
    float s0=0.f, s1=0.f;
    for(int i=t;i<SCORE_BLOCKS;i+=256){ s0 += partials[2*i]; s1 += partials[2*i+1]; }
    sh0[t]=s0; sh1[t]=s1; __syncthreads();
    for(int s=128;s>0;s>>=1){ if(t<s){ sh0[t]+=sh0[t+s]; sh1[t]+=sh1[t+s]; } __syncthreads(); }
    if(t==0){ scores[0]=sh0[0]; scores[1]=sh1[0]; }
}

// ---------------- final — LDS-tiled, z precomputed in LDS, f32 out
__global__ __launch_bounds__(128) void final_v2(
    const ushort16* __restrict__ o_em, const ushort16* __restrict__ o_mm,
    const float* __restrict__ Wl, const float* __restrict__ blv,
    const float* __restrict__ scores, float* __restrict__ out)
{
    __shared__ float wlds[64*129];       // f32 W, row stride 129 (bank-conflict-free)
    __shared__ float zlds[NT*128];
    int t = threadIdx.x;
    for(int i=t;i<2048;i+=128){          // 64x128 f32 = 2048 float4
        float4 v = ((const float4*)Wl)[i];
        int r = i >> 5, k4 = i & 31;
        float* d = wlds + r*129 + k4*4;
        d[0]=v.x; d[1]=v.y; d[2]=v.z; d[3]=v.w;
    }
    float s0 = scores[0]*(1.0f/N_MATN), s1 = scores[1]*(1.0f/N_MATN);
    float mx = fmaxf(s0,s1);
    float e0 = __expf(s0-mx), e1 = __expf(s1-mx);
    float inv = 1.0f/(e0+e1);
    float a0 = e0*inv, a1 = e1*inv;
    int j = t & 63, half = t >> 6;
    float bj = blv[j];
    const float* wr = wlds + j*129;
    __syncthreads();
    for(int tile = blockIdx.x; tile < NTILES; tile += gridDim.x){
        int n0 = tile*NT;
        __syncthreads();
        {   // stage z = a0*o_em + a1*o_mm : thread t covers elems 8t..8t+7
            const uint4* pe = (const uint4*)((const uint32*)o_em + (size_t)n0*64);
            const uint4* pm = (const uint4*)((const uint32*)o_mm + (size_t)n0*64);
            uint4 ve = pe[t], vm = pm[t];
            float* zd = zlds + t*8;
            zd[0]=a0*blo(ve.x)+a1*blo(vm.x); zd[1]=a0*bhi(ve.x)+a1*bhi(vm.x);
            zd[2]=a0*blo(ve.y)+a1*blo(vm.y); zd[3]=a0*bhi(ve.y)+a1*bhi(vm.y);
            zd[4]=a0*blo(ve.z)+a1*blo(vm.z); zd[5]=a0*bhi(ve.z)+a1*bhi(vm.z);
            zd[6]=a0*blo(ve.w)+a1*blo(vm.w); zd[7]=a0*bhi(ve.w)+a1*bhi(vm.w);
        }
        __syncthreads();
        float acc[4] = {0.f,0.f,0.f,0.f};
        #pragma unroll
        for(int kk=0;kk<128;kk+=8){
            float f0=wr[kk],f1=wr[kk+1],f2=wr[kk+2],f3=wr[kk+3];
            float f4=wr[kk+4],f5=wr[kk+5],f6=wr[kk+6],f7=wr[kk+7];
            #pragma unroll
            for(int n=0;n<4;n++){
                const float* zr = zlds + (half*4+n)*128 + kk;
                acc[n] += zr[0]*f0 + zr[1]*f1 + zr[2]*f2 + zr[3]*f3
                        + zr[4]*f4 + zr[5]*f5 + zr[6]*f6 + zr[7]*f7;
            }
        }
        #pragma unroll
        for(int n=0;n<4;n++)
            out[(size_t)(n0 + half*4 + n)*OUTC + j] = bj + acc[n];
    }
}

extern "C" void kernel_launch(void* const* d_in, const int* in_sizes, int n_in,
                              void* d_out, int out_size, void* d_ws, size_t ws_size,
                              hipStream_t stream)
{
    const float* x_mat    = (const float*)d_in[0];
    const float* x_elem   = (const float*)d_in[1];
    const float* W_pm     = (const float*)d_in[2];
    const float* b_pm     = (const float*)d_in[3];
    const float* W_pe     = (const float*)d_in[4];
    const float* b_pe     = (const float*)d_in[5];
    const float* a_se     = (const float*)d_in[6];
    const float* a_de     = (const float*)d_in[7];
    const float* a_sm     = (const float*)d_in[8];
    const float* a_dm     = (const float*)d_in[9];
    const float* Wk       = (const float*)d_in[10];
    const float* bk       = (const float*)d_in[11];
    const float* qv       = (const float*)d_in[12];
    const float* Wl       = (const float*)d_in[13];
    const float* bl       = (const float*)d_in[14];
    const int* src_em     = (const int*)d_in[15];
    const int* dst_em     = (const int*)d_in[16];
    const int* src_mm     = (const int*)d_in[17];
    const int* dst_mm     = (const int*)d_in[18];
    int nE_em = in_sizes[15];
    int nE_mm = in_sizes[17];

    char* ws = (char*)d_ws;
    size_t off = 0;
    auto alloc = [&](size_t bytes) -> void* {
        void* p = ws + off; off += (bytes + 255) & ~size_t(255); return p;
    };
    ushort16* h_mat   = (ushort16*)alloc((size_t)N_MATN*HIDN*2);
    ushort16* h_elem  = (ushort16*)alloc((size_t)N_ELEMN*HIDN*2);
    float*    asrcEM  = (float*)   alloc((size_t)N_ELEMN*NHEAD*4);
    float*    adstEM  = (float*)   alloc((size_t)N_MATN*NHEAD*4);
    float*    asrcMM  = (float*)   alloc((size_t)N_MATN*NHEAD*4);
    float*    adstMM  = (float*)   alloc((size_t)N_MATN*NHEAD*4);
    int*      offs_em = (int*)     alloc((size_t)(N_MATN+1)*4);
    int*      offs_mm = (int*)     alloc((size_t)(N_MATN+1)*4);
    int*      csr_em  = (int*)     alloc((size_t)1000000*4);
    int*      csr_mm  = (int*)     alloc((size_t)2000000*4);
    ushort16* o_em    = (ushort16*)alloc((size_t)N_MATN*HIDN*2);
    ushort16* o_mm    = (ushort16*)alloc((size_t)N_MATN*HIDN*2);
    float*    partials= (float*)   alloc((size_t)SCORE_BLOCKS*2*4);
    float*    scores  = (float*)   alloc(256);
    size_t zero_start = off;
    int*      deg_em  = (int*)     alloc((size_t)N_MATN*4);
    int*      deg_mm  = (int*)     alloc((size_t)N_MATN*4);
    size_t zero_bytes = off - zero_start;

    hipMemsetAsync(ws + zero_start, 0, zero_bytes, stream);

    proj_elem_v2<<<N_ELEMN, 128, 0, stream>>>(x_elem, W_pe, b_pe, a_se, h_elem, asrcEM);
    proj_mat_v2<<<1024, 128, 0, stream>>>(x_mat, W_pm, b_pm, a_de, a_sm, a_dm,
                                          h_mat, adstEM, asrcMM, adstMM);

    count_kernel<<<1024, 256, 0, stream>>>(dst_em, nE_em, deg_em);
    count_kernel<<<1024, 256, 0, stream>>>(dst_mm, nE_mm, deg_mm);
    scan_kernel<<<1, 256, 0, stream>>>(deg_em, offs_em);
    scan_kernel<<<1, 256, 0, stream>>>(deg_mm, offs_mm);
    copy_kernel<<<256, 256, 0, stream>>>(offs_em, deg_em, N_MATN);
    copy_kernel<<<256, 256, 0, stream>>>(offs_mm, deg_mm, N_MATN);
    scatter_kernel<<<1024, 256, 0, stream>>>(src_em, dst_em, nE_em, deg_em, csr_em);
    scatter_kernel<<<1024, 256, 0, stream>>>(src_mm, dst_mm, nE_mm, deg_mm, csr_mm);

    agg_kernel<<<2048, 256, 0, stream>>>(offs_em, csr_em, h_elem, asrcEM, adstEM, o_em);
    agg_kernel<<<2048, 256, 0, stream>>>(offs_mm, csr_mm, h_mat, asrcMM, adstMM, o_mm);

    score_v2<<<SCORE_BLOCKS, 128, 0, stream>>>(o_em, o_mm, Wk, bk, qv, partials);
    reduce_scores_kernel<<<1, 256, 0, stream>>>(partials, scores);
    final_v2<<<1024, 128, 0, stream>>>(o_em, o_mm, Wl, bl, scores, (float*)d_out);
}

// Round 7
// 1522.693 us; speedup vs baseline: 2.5626x; 2.5626x over previous
//
#include <hip/hip_runtime.h>
#include <hip/hip_bf16.h>

typedef unsigned int uint32;
typedef unsigned short ushort16;

#define N_MATN 100000
#define N_ELEMN 118
#define F_MATN 128
#define F_ELEMN 64
#define HIDN 128
#define NHEAD 8
#define OUTC 64
#define SCORE_BLOCKS 1024
#define NT 8                      // nodes per tile
#define NTILES (N_MATN/NT)        // 12500 exactly

__device__ __forceinline__ float blo(uint32 u){ return __uint_as_float(u << 16); }
__device__ __forceinline__ float bhi(uint32 u){ return __uint_as_float(u & 0xffff0000u); }
__device__ __forceinline__ ushort16 f2bf(float f){
    uint32 u = __float_as_uint(f);
    uint32 r = u + 0x7FFFu + ((u >> 16) & 1u);   // RNE
    return (ushort16)(r >> 16);
}
__device__ __forceinline__ uint32 pack2(float a, float b){
    return (uint32)f2bf(a) | ((uint32)f2bf(b) << 16);
}

// ---------------- projection: elem nodes — one block per node
__global__ __launch_bounds__(128) void proj_elem_v2(
    const float* __restrict__ x, const float* __restrict__ W,
    const float* __restrict__ bias, const float* __restrict__ a_se,
    ushort16* __restrict__ h, float* __restrict__ asrc_em)
{
    __shared__ float xr[F_ELEMN];
    int n = blockIdx.x, c = threadIdx.x;
    if(c < 16) ((float4*)xr)[c] = ((const float4*)(x + n*F_ELEMN))[c];
    __syncthreads();
    const float4* Wr = (const float4*)(W + c*F_ELEMN);
    float acc = 0.f;
    #pragma unroll 4
    for(int i=0;i<16;i++){
        float4 w = Wr[i];
        acc += xr[4*i]*w.x + xr[4*i+1]*w.y + xr[4*i+2]*w.z + xr[4*i+3]*w.w;
    }
    acc += bias[c];
    h[n*HIDN + c] = f2bf(acc);
    float p = acc * a_se[c];
    #pragma unroll
    for(int m=8;m>=1;m>>=1) p += __shfl_xor(p, m, 16);
    if((c&15)==0) asrc_em[n*NHEAD + (c>>4)] = p;
}

// ---------------- projection: mat nodes — LDS bf16 W + bf16 x tile, unroll-pinned
__global__ __launch_bounds__(128) void proj_mat_v3(
    const float* __restrict__ x, const float* __restrict__ W,
    const float* __restrict__ bias,
    const float* __restrict__ a_de, const float* __restrict__ a_sm, const float* __restrict__ a_dm,
    ushort16* __restrict__ h,
    float* __restrict__ adst_em, float* __restrict__ asrc_mm, float* __restrict__ adst_mm)
{
    __shared__ uint32 wlds[128*65];       // bf16 W, row stride 65 (2-way scalar reads = free)
    __shared__ uint32 xlds[NT*64];        // bf16 x tile, node row = 64 uints (16B-aligned b128 broadcast)
    int t = threadIdx.x;
    {   // stage W row t as bf16 pairs (unroll pinned: keep prologue VGPR watermark low)
        const float4* Wr = (const float4*)(W + t*F_MATN);
        uint32* wrow_s = wlds + t*65;
        #pragma unroll 2
        for(int i=0;i<32;i++){
            float4 v = Wr[i];
            wrow_s[2*i]   = pack2(v.x, v.y);
            wrow_s[2*i+1] = pack2(v.z, v.w);
        }
    }
    float bc = bias[t];
    float ade = a_de[t], asm_ = a_sm[t], adm = a_dm[t];
    int hh = t >> 4;
    const uint32* wrow = wlds + t*65;
    __syncthreads();
    for(int tile = blockIdx.x; tile < NTILES; tile += gridDim.x){
        int n0 = tile*NT;
        __syncthreads();      // previous tile's xlds readers done
        {   // stage x tile bf16: 8 nodes x 32 float4; thread t packs float4 idx t and t+128
            const float4* xs = (const float4*)(x + (size_t)n0*F_MATN);
            float4 v0 = xs[t], v1 = xs[t+128];
            int n_a = t >> 5,        f_a = t & 31;
            int n_b = (t+128) >> 5,  f_b = t & 31;
            xlds[n_a*64 + 2*f_a    ] = pack2(v0.x, v0.y);
            xlds[n_a*64 + 2*f_a + 1] = pack2(v0.z, v0.w);
            xlds[n_b*64 + 2*f_b    ] = pack2(v1.x, v1.y);
            xlds[n_b*64 + 2*f_b + 1] = pack2(v1.z, v1.w);
        }
        __syncthreads();
        float acc[NT];
        #pragma unroll
        for(int n=0;n<NT;n++) acc[n] = 0.f;
        #pragma unroll 1
        for(int kk=0;kk<64;kk+=4){        // 8 k per iteration
            uint32 w0=wrow[kk], w1=wrow[kk+1], w2=wrow[kk+2], w3=wrow[kk+3];
            float f0=blo(w0),f1=bhi(w0),f2=blo(w1),f3=bhi(w1);
            float f4=blo(w2),f5=bhi(w2),f6=blo(w3),f7=bhi(w3);
            #pragma unroll
            for(int n=0;n<NT;n++){
                uint4 xv = *(const uint4*)(xlds + n*64 + kk);   // broadcast b128
                acc[n] += blo(xv.x)*f0 + bhi(xv.x)*f1 + blo(xv.y)*f2 + bhi(xv.y)*f3
                        + blo(xv.z)*f4 + bhi(xv.z)*f5 + blo(xv.w)*f6 + bhi(xv.w)*f7;
            }
        }
        #pragma unroll 1
        for(int n=0;n<NT;n++){
            float a = acc[n] + bc;
            h[(size_t)(n0+n)*HIDN + t] = f2bf(a);
            float p0 = a*ade, p1 = a*asm_, p2 = a*adm;
            #pragma unroll
            for(int m=8;m>=1;m>>=1){
                p0 += __shfl_xor(p0, m, 16);
                p1 += __shfl_xor(p1, m, 16);
                p2 += __shfl_xor(p2, m, 16);
            }
            if((t&15)==0){
                adst_em[(n0+n)*NHEAD+hh]=p0;
                asrc_mm[(n0+n)*NHEAD+hh]=p1;
                adst_mm[(n0+n)*NHEAD+hh]=p2;
            }
        }
    }
}

// ---------------- CSR build (unchanged)
__global__ __launch_bounds__(256) void count_kernel(
    const int* __restrict__ dst, int nE, int* __restrict__ deg)
{
    int i = blockIdx.x*blockDim.x + threadIdx.x;
    int st = gridDim.x*blockDim.x;
    for(; i < nE; i += st) atomicAdd(&deg[dst[i]], 1);
}

__global__ __launch_bounds__(256) void scan_kernel(
    const int* __restrict__ deg, int* __restrict__ offs)
{
    __shared__ int part[256];
    int t = threadIdx.x;
    const int CH = (N_MATN + 255) >> 8;
    int beg = t*CH;
    int end = beg + CH; if(end > N_MATN) end = N_MATN;
    int s = 0;
    for(int i = beg; i < end; i++) s += deg[i];
    part[t] = s;
    __syncthreads();
    if(t == 0){
        int run = 0;
        for(int i = 0; i < 256; i++){ int v = part[i]; part[i] = run; run += v; }
    }
    __syncthreads();
    int run = part[t];
    for(int i = beg; i < end; i++){ offs[i] = run; run += deg[i]; }
    if(t == 255) offs[N_MATN] = run;
}

__global__ __launch_bounds__(256) void copy_kernel(
    const int* __restrict__ a, int* __restrict__ b, int n)
{
    int i = blockIdx.x*blockDim.x + threadIdx.x;
    int st = gridDim.x*blockDim.x;
    for(; i < n; i += st) b[i] = a[i];
}

__global__ __launch_bounds__(256) void scatter_kernel(
    const int* __restrict__ src, const int* __restrict__ dst, int nE,
    int* __restrict__ cur, int* __restrict__ csr)
{
    int i = blockIdx.x*blockDim.x + threadIdx.x;
    int st = gridDim.x*blockDim.x;
    for(; i < nE; i += st){
        int d = dst[i];
        int p = atomicAdd(&cur[d], 1);
        csr[p] = src[i];
    }
}

// ---------------- aggregation (unchanged)
__global__ __launch_bounds__(256) void agg_kernel(
    const int* __restrict__ offs, const int* __restrict__ csr,
    const ushort16* __restrict__ hsrc, const float* __restrict__ asrc,
    const float* __restrict__ adst, ushort16* __restrict__ o)
{
    int lane = threadIdx.x & 63;
    int w = (blockIdx.x*blockDim.x + threadIdx.x) >> 6;
    int nw = (gridDim.x*blockDim.x) >> 6;
    int hh = lane >> 3;
    for(int d = w; d < N_MATN; d += nw){
        int beg = offs[d], end = offs[d+1];
        float ad = adst[d*NHEAD + hh];
        float den = 0.f, n0 = 0.f, n1 = 0.f;
        for(int j = beg; j < end; j++){
            int s = csr[j];
            float al = asrc[s*NHEAD + hh] + ad;
            al = al > 0.f ? al : 0.2f*al;
            float ex = __expf(al);
            den += ex;
            uint32 hv = ((const uint32*)hsrc)[s*64 + lane];
            n0 += blo(hv)*ex;
            n1 += bhi(hv)*ex;
        }
        float rdn = 1.0f/(den + 1e-16f);
        uint32 pk = (uint32)f2bf(fmaxf(n0*rdn, 0.f)) | ((uint32)f2bf(fmaxf(n1*rdn, 0.f)) << 16);
        ((uint32*)o)[(size_t)d*64 + lane] = pk;
    }
}

// ---------------- semantic scores — LDS-tiled, unroll-pinned
__global__ __launch_bounds__(128) void score_v3(
    const ushort16* __restrict__ o_em, const ushort16* __restrict__ o_mm,
    const float* __restrict__ Wk, const float* __restrict__ bkv,
    const float* __restrict__ qv, float* __restrict__ partials)
{
    __shared__ uint32 wlds[128*65];
    __shared__ uint32 xe[NT*64], xm[NT*64];
    int t = threadIdx.x;
    {
        const float4* Wr = (const float4*)(Wk + t*HIDN);
        uint32* wrow_s = wlds + t*65;
        #pragma unroll 2
        for(int i=0;i<32;i++){
            float4 v = Wr[i];
            wrow_s[2*i]   = pack2(v.x, v.y);
            wrow_s[2*i+1] = pack2(v.z, v.w);
        }
    }
    float bc = bkv[t], qc = qv[t];
    const uint32* wrow = wlds + t*65;
    float se = 0.f, sm = 0.f;
    __syncthreads();
    for(int tile = blockIdx.x; tile < NTILES; tile += gridDim.x){
        int n0 = tile*NT;
        __syncthreads();
        {   // stage o tiles: 8 nodes x 64 uints each = 128 uint4 per matrix
            const uint4* pe = (const uint4*)((const uint32*)o_em + (size_t)n0*64);
            const uint4* pm = (const uint4*)((const uint32*)o_mm + (size_t)n0*64);
            ((uint4*)xe)[t] = pe[t];
            ((uint4*)xm)[t] = pm[t];
        }
        __syncthreads();
        float ae[NT], am[NT];
        #pragma unroll
        for(int n=0;n<NT;n++){ ae[n]=0.f; am[n]=0.f; }
        #pragma unroll 1
        for(int kk=0;kk<64;kk+=4){
            uint32 w0=wrow[kk], w1=wrow[kk+1], w2=wrow[kk+2], w3=wrow[kk+3];
            float f0=blo(w0),f1=bhi(w0),f2=blo(w1),f3=bhi(w1);
            float f4=blo(w2),f5=bhi(w2),f6=blo(w3),f7=bhi(w3);
            #pragma unroll
            for(int n=0;n<NT;n++){
                uint4 e = *(const uint4*)(xe + n*64 + kk);
                ae[n] += blo(e.x)*f0 + bhi(e.x)*f1 + blo(e.y)*f2 + bhi(e.y)*f3
                       + blo(e.z)*f4 + bhi(e.z)*f5 + blo(e.w)*f6 + bhi(e.w)*f7;
                uint4 m = *(const uint4*)(xm + n*64 + kk);
                am[n] += blo(m.x)*f0 + bhi(m.x)*f1 + blo(m.y)*f2 + bhi(m.y)*f3
                       + blo(m.z)*f4 + bhi(m.z)*f5 + blo(m.w)*f6 + bhi(m.w)*f7;
            }
        }
        #pragma unroll 1
        for(int n=0;n<NT;n++){
            se += qc * tanhf(ae[n] + bc);
            sm += qc * tanhf(am[n] + bc);
        }
    }
    #pragma unroll
    for(int m=32;m>=1;m>>=1){ se += __shfl_xor(se,m); sm += __shfl_xor(sm,m); }
    __shared__ float red[4];
    int wv = t >> 6, ln = t & 63;
    if(ln==0){ red[wv*2]=se; red[wv*2+1]=sm; }
    __syncthreads();
    if(t==0){
        partials[blockIdx.x*2+0] = red[0]+red[2];
        partials[blockIdx.x*2+1] = red[1]+red[3];
    }
}

__global__ __launch_bounds__(256) void reduce_scores_kernel(
    const float* __restrict__ partials, float* __restrict__ scores)
{
    __shared__ float sh0[256], sh1[256];
    int t = threadIdx.x;
    float s0=0.f, s1=0.f;
    for(int i=t;i<SCORE_BLOCKS;i+=256){ s0 += partials[2*i]; s1 += partials[2*i+1]; }
    sh0[t]=s0; sh1[t]=s1; __syncthreads();
    for(int s=128;s>0;s>>=1){ if(t<s){ sh0[t]+=sh0[t+s]; sh1[t]+=sh1[t+s]; } __syncthreads(); }
    if(t==0){ scores[0]=sh0[0]; scores[1]=sh1[0]; }
}

// ---------------- final — LDS-tiled, z f32 in LDS (b128 broadcast reads), unroll-pinned
__global__ __launch_bounds__(128) void final_v3(
    const ushort16* __restrict__ o_em, const ushort16* __restrict__ o_mm,
    const float* __restrict__ Wl, const float* __restrict__ blv,
    const float* __restrict__ scores, float* __restrict__ out)
{
    __shared__ float wlds[64*129];       // f32 W, row stride 129 (scalar reads 2-way = free)
    __shared__ float zlds[NT*128];
    int t = threadIdx.x;
    #pragma unroll 2
    for(int i=t;i<2048;i+=128){          // 64x128 f32 = 2048 float4
        float4 v = ((const float4*)Wl)[i];
        int r = i >> 5, k4 = i & 31;
        float* d = wlds + r*129 + k4*4;
        d[0]=v.x; d[1]=v.y; d[2]=v.z; d[3]=v.w;
    }
    float s0 = scores[0]*(1.0f/N_MATN), s1 = scores[1]*(1.0f/N_MATN);
    float mx = fmaxf(s0,s1);
    float e0 = __expf(s0-mx), e1 = __expf(s1-mx);
    float inv = 1.0f/(e0+e1);
    float a0 = e0*inv, a1 = e1*inv;
    int j = t & 63, half = t >> 6;
    float bj = blv[j];
    const float* wr = wlds + j*129;
    __syncthreads();
    for(int tile = blockIdx.x; tile < NTILES; tile += gridDim.x){
        int n0 = tile*NT;
        __syncthreads();
        {   // stage z = a0*o_em + a1*o_mm : thread t covers elems 8t..8t+7
            const uint4* pe = (const uint4*)((const uint32*)o_em + (size_t)n0*64);
            const uint4* pm = (const uint4*)((const uint32*)o_mm + (size_t)n0*64);
            uint4 ve = pe[t], vm = pm[t];
            float* zd = zlds + t*8;
            zd[0]=a0*blo(ve.x)+a1*blo(vm.x); zd[1]=a0*bhi(ve.x)+a1*bhi(vm.x);
            zd[2]=a0*blo(ve.y)+a1*blo(vm.y); zd[3]=a0*bhi(ve.y)+a1*bhi(vm.y);
            zd[4]=a0*blo(ve.z)+a1*blo(vm.z); zd[5]=a0*bhi(ve.z)+a1*bhi(vm.z);
            zd[6]=a0*blo(ve.w)+a1*blo(vm.w); zd[7]=a0*bhi(ve.w)+a1*bhi(vm.w);
        }
        __syncthreads();
        float acc[4] = {0.f,0.f,0.f,0.f};
        #pragma unroll 1
        for(int kk=0;kk<128;kk+=8){
            float f0=wr[kk],f1=wr[kk+1],f2=wr[kk+2],f3=wr[kk+3];
            float f4=wr[kk+4],f5=wr[kk+5],f6=wr[kk+6],f7=wr[kk+7];
            #pragma unroll
            for(int n=0;n<4;n++){
                const float4* zr = (const float4*)(zlds + (half*4+n)*128 + kk);  // b128 broadcast
                float4 za = zr[0], zb = zr[1];
                acc[n] += za.x*f0 + za.y*f1 + za.z*f2 + za.w*f3
                        + zb.x*f4 + zb.y*f5 + zb.z*f6 + zb.w*f7;
            }
        }
        #pragma unroll
        for(int n=0;n<4;n++)
            out[(size_t)(n0 + half*4 + n)*OUTC + j] = bj + acc[n];
    }
}

extern "C" void kernel_launch(void* const* d_in, const int* in_sizes, int n_in,
                              void* d_out, int out_size, void* d_ws, size_t ws_size,
                              hipStream_t stream)
{
    const float* x_mat    = (const float*)d_in[0];
    const float* x_elem   = (const float*)d_in[1];
    const float* W_pm     = (const float*)d_in[2];
    const float* b_pm     = (const float*)d_in[3];
    const float* W_pe     = (const float*)d_in[4];
    const float* b_pe     = (const float*)d_in[5];
    const float* a_se     = (const float*)d_in[6];
    const float* a_de     = (const float*)d_in[7];
    const float* a_sm     = (const float*)d_in[8];
    const float* a_dm     = (const float*)d_in[9];
    const float* Wk       = (const float*)d_in[10];
    const float* bk       = (const float*)d_in[11];
    const float* qv       = (const float*)d_in[12];
    const float* Wl       = (const float*)d_in[13];
    const float* bl       = (const float*)d_in[14];
    const int* src_em     = (const int*)d_in[15];
    const int* dst_em     = (const int*)d_in[16];
    const int* src_mm     = (const int*)d_in[17];
    const int* dst_mm     = (const int*)d_in[18];
    int nE_em = in_sizes[15];
    int nE_mm = in_sizes[17];

    char* ws = (char*)d_ws;
    size_t off = 0;
    auto alloc = [&](size_t bytes) -> void* {
        void* p = ws + off; off += (bytes + 255) & ~size_t(255); return p;
    };
    ushort16* h_mat   = (ushort16*)alloc((size_t)N_MATN*HIDN*2);
    ushort16* h_elem  = (ushort16*)alloc((size_t)N_ELEMN*HIDN*2);
    float*    asrcEM  = (float*)   alloc((size_t)N_ELEMN*NHEAD*4);
    float*    adstEM  = (float*)   alloc((size_t)N_MATN*NHEAD*4);
    float*    asrcMM  = (float*)   alloc((size_t)N_MATN*NHEAD*4);
    float*    adstMM  = (float*)   alloc((size_t)N_MATN*NHEAD*4);
    int*      offs_em = (int*)     alloc((size_t)(N_MATN+1)*4);
    int*      offs_mm = (int*)     alloc((size_t)(N_MATN+1)*4);
    int*      csr_em  = (int*)     alloc((size_t)1000000*4);
    int*      csr_mm  = (int*)     alloc((size_t)2000000*4);
    ushort16* o_em    = (ushort16*)alloc((size_t)N_MATN*HIDN*2);
    ushort16* o_mm    = (ushort16*)alloc((size_t)N_MATN*HIDN*2);
    float*    partials= (float*)   alloc((size_t)SCORE_BLOCKS*2*4);
    float*    scores  = (float*)   alloc(256);
    size_t zero_start = off;
    int*      deg_em  = (int*)     alloc((size_t)N_MATN*4);
    int*      deg_mm  = (int*)     alloc((size_t)N_MATN*4);
    size_t zero_bytes = off - zero_start;

    hipMemsetAsync(ws + zero_start, 0, zero_bytes, stream);

    proj_elem_v2<<<N_ELEMN, 128, 0, stream>>>(x_elem, W_pe, b_pe, a_se, h_elem, asrcEM);
    proj_mat_v3<<<1024, 128, 0, stream>>>(x_mat, W_pm, b_pm, a_de, a_sm, a_dm,
                                          h_mat, adstEM, asrcMM, adstMM);

    count_kernel<<<1024, 256, 0, stream>>>(dst_em, nE_em, deg_em);
    count_kernel<<<1024, 256, 0, stream>>>(dst_mm, nE_mm, deg_mm);
    scan_kernel<<<1, 256, 0, stream>>>(deg_em, offs_em);
    scan_kernel<<<1, 256, 0, stream>>>(deg_mm, offs_mm);
    copy_kernel<<<256, 256, 0, stream>>>(offs_em, deg_em, N_MATN);
    copy_kernel<<<256, 256, 0, stream>>>(offs_mm, deg_mm, N_MATN);
    scatter_kernel<<<1024, 256, 0, stream>>>(src_em, dst_em, nE_em, deg_em, csr_em);
    scatter_kernel<<<1024, 256, 0, stream>>>(src_mm, dst_mm, nE_mm, deg_mm, csr_mm);

    agg_kernel<<<2048, 256, 0, stream>>>(offs_em, csr_em, h_elem, asrcEM, adstEM, o_em);
    agg_kernel<<<2048, 256, 0, stream>>>(offs_mm, csr_mm, h_mat, asrcMM, adstMM, o_mm);

    score_v3<<<SCORE_BLOCKS, 128, 0, stream>>>(o_em, o_mm, Wk, bk, qv, partials);
    reduce_scores_kernel<<<1, 256, 0, stream>>>(partials, scores);
    final_v3<<<1024, 128, 0, stream>>>(o_em, o_mm, Wl, bl, scores, (float*)d_out);
}

// Round 8
// 1239.869 us; speedup vs baseline: 3.1471x; 1.2281x over previous
//
#include <hip/hip_runtime.h>
#include <hip/hip_bf16.h>

typedef unsigned int uint32;
typedef unsigned short ushort16;

using bf16x8 = __attribute__((ext_vector_type(8))) short;
using f32x4  = __attribute__((ext_vector_type(4))) float;

#define N_MATN 100000
#define N_ELEMN 118
#define F_MATN 128
#define F_ELEMN 64
#define HIDN 128
#define NHEAD 8
#define OUTC 64
#define SCORE_BLOCKS 1024
#define NSTRIPS 6250              // 100000 / 16
#define NT 8
#define NTILES (N_MATN/NT)

__device__ __forceinline__ float blo(uint32 u){ return __uint_as_float(u << 16); }
__device__ __forceinline__ float bhi(uint32 u){ return __uint_as_float(u & 0xffff0000u); }
__device__ __forceinline__ ushort16 f2bf(float f){
    uint32 u = __float_as_uint(f);
    uint32 r = u + 0x7FFFu + ((u >> 16) & 1u);   // RNE
    return (ushort16)(r >> 16);
}
__device__ __forceinline__ uint32 pack2(float a, float b){
    return (uint32)f2bf(a) | ((uint32)f2bf(b) << 16);
}
__device__ __forceinline__ bf16x8 cvt8(const float* __restrict__ p){
    bf16x8 r;
    #pragma unroll
    for(int j=0;j<8;j++) r[j] = (short)f2bf(p[j]);
    return r;
}

// ---------------- projection: elem nodes — one block per node (unchanged)
__global__ __launch_bounds__(128) void proj_elem_v2(
    const float* __restrict__ x, const float* __restrict__ W,
    const float* __restrict__ bias, const float* __restrict__ a_se,
    ushort16* __restrict__ h, float* __restrict__ asrc_em)
{
    __shared__ float xr[F_ELEMN];
    int n = blockIdx.x, c = threadIdx.x;
    if(c < 16) ((float4*)xr)[c] = ((const float4*)(x + n*F_ELEMN))[c];
    __syncthreads();
    const float4* Wr = (const float4*)(W + c*F_ELEMN);
    float acc = 0.f;
    #pragma unroll 4
    for(int i=0;i<16;i++){
        float4 w = Wr[i];
        acc += xr[4*i]*w.x + xr[4*i+1]*w.y + xr[4*i+2]*w.z + xr[4*i+3]*w.w;
    }
    acc += bias[c];
    h[n*HIDN + c] = f2bf(acc);
    float p = acc * a_se[c];
    #pragma unroll
    for(int m=8;m>=1;m>>=1) p += __shfl_xor(p, m, 16);
    if((c&15)==0) asrc_em[n*NHEAD + (c>>4)] = p;
}

// ---------------- projection: mat nodes — MFMA 16x16x32 bf16
// block = 4 waves sharing one 16-node strip; wave w owns c-tiles {2w,2w+1} (= heads)
__global__ __launch_bounds__(256) void proj_mat_mfma(
    const float* __restrict__ x, const float* __restrict__ W,
    const float* __restrict__ bias,
    const float* __restrict__ a_de, const float* __restrict__ a_sm, const float* __restrict__ a_dm,
    ushort16* __restrict__ h,
    float* __restrict__ adst_em, float* __restrict__ asrc_mm, float* __restrict__ adst_mm)
{
    int tid = threadIdx.x;
    int wv = tid >> 6, lane = tid & 63, quad = lane >> 4, sl = lane & 15;
    bf16x8 B[2][4];
    float bc[2], ade[2], asv[2], adv[2];
    #pragma unroll
    for(int i=0;i<2;i++){
        int c = (2*wv+i)*16 + sl;
        const float* wr = W + c*F_MATN;
        #pragma unroll
        for(int ks=0;ks<4;ks++) B[i][ks] = cvt8(wr + ks*32 + quad*8);
        bc[i] = bias[c]; ade[i] = a_de[c]; asv[i] = a_sm[c]; adv[i] = a_dm[c];
    }
    for(int s = blockIdx.x; s < NSTRIPS; s += gridDim.x){
        int n0 = s*16;
        const float* xrow = x + (size_t)(n0+sl)*F_MATN;
        bf16x8 A[4];
        #pragma unroll
        for(int ks=0;ks<4;ks++) A[ks] = cvt8(xrow + ks*32 + quad*8);
        f32x4 acc[2];
        #pragma unroll
        for(int i=0;i<2;i++){ acc[i][0]=0.f; acc[i][1]=0.f; acc[i][2]=0.f; acc[i][3]=0.f; }
        #pragma unroll
        for(int i=0;i<2;i++)
            #pragma unroll
            for(int ks=0;ks<4;ks++)
                acc[i] = __builtin_amdgcn_mfma_f32_16x16x32_bf16(A[ks], B[i][ks], acc[i], 0, 0, 0);
        #pragma unroll
        for(int i=0;i<2;i++){
            int head = 2*wv + i;
            #pragma unroll
            for(int r=0;r<4;r++){
                float a = acc[i][r] + bc[i];
                int node = n0 + quad*4 + r;
                h[(size_t)node*HIDN + head*16 + sl] = f2bf(a);
                float p0 = a*ade[i], p1 = a*asv[i], p2 = a*adv[i];
                #pragma unroll
                for(int m=8;m>=1;m>>=1){
                    p0 += __shfl_xor(p0, m);
                    p1 += __shfl_xor(p1, m);
                    p2 += __shfl_xor(p2, m);
                }
                if(sl == 0){
                    adst_em[node*NHEAD + head] = p0;
                    asrc_mm[node*NHEAD + head] = p1;
                    adst_mm[node*NHEAD + head] = p2;
                }
            }
        }
    }
}

// ---------------- CSR build (unchanged)
__global__ __launch_bounds__(256) void count_kernel(
    const int* __restrict__ dst, int nE, int* __restrict__ deg)
{
    int i = blockIdx.x*blockDim.x + threadIdx.x;
    int st = gridDim.x*blockDim.x;
    for(; i < nE; i += st) atomicAdd(&deg[dst[i]], 1);
}

__global__ __launch_bounds__(256) void scan_kernel(
    const int* __restrict__ deg, int* __restrict__ offs)
{
    __shared__ int part[256];
    int t = threadIdx.x;
    const int CH = (N_MATN + 255) >> 8;
    int beg = t*CH;
    int end = beg + CH; if(end > N_MATN) end = N_MATN;
    int s = 0;
    for(int i = beg; i < end; i++) s += deg[i];
    part[t] = s;
    __syncthreads();
    if(t == 0){
        int run = 0;
        for(int i = 0; i < 256; i++){ int v = part[i]; part[i] = run; run += v; }
    }
    __syncthreads();
    int run = part[t];
    for(int i = beg; i < end; i++){ offs[i] = run; run += deg[i]; }
    if(t == 255) offs[N_MATN] = run;
}

__global__ __launch_bounds__(256) void copy_kernel(
    const int* __restrict__ a, int* __restrict__ b, int n)
{
    int i = blockIdx.x*blockDim.x + threadIdx.x;
    int st = gridDim.x*blockDim.x;
    for(; i < n; i += st) b[i] = a[i];
}

__global__ __launch_bounds__(256) void scatter_kernel(
    const int* __restrict__ src, const int* __restrict__ dst, int nE,
    int* __restrict__ cur, int* __restrict__ csr)
{
    int i = blockIdx.x*blockDim.x + threadIdx.x;
    int st = gridDim.x*blockDim.x;
    for(; i < nE; i += st){
        int d = dst[i];
        int p = atomicAdd(&cur[d], 1);
        csr[p] = src[i];
    }
}

// ---------------- aggregation (unchanged)
__global__ __launch_bounds__(256) void agg_kernel(
    const int* __restrict__ offs, const int* __restrict__ csr,
    const ushort16* __restrict__ hsrc, const float* __restrict__ asrc,
    const float* __restrict__ adst, ushort16* __restrict__ o)
{
    int lane = threadIdx.x & 63;
    int w = (blockIdx.x*blockDim.x + threadIdx.x) >> 6;
    int nw = (gridDim.x*blockDim.x) >> 6;
    int hh = lane >> 3;
    for(int d = w; d < N_MATN; d += nw){
        int beg = offs[d], end = offs[d+1];
        float ad = adst[d*NHEAD + hh];
        float den = 0.f, n0 = 0.f, n1 = 0.f;
        for(int j = beg; j < end; j++){
            int s = csr[j];
            float al = asrc[s*NHEAD + hh] + ad;
            al = al > 0.f ? al : 0.2f*al;
            float ex = __expf(al);
            den += ex;
            uint32 hv = ((const uint32*)hsrc)[s*64 + lane];
            n0 += blo(hv)*ex;
            n1 += bhi(hv)*ex;
        }
        float rdn = 1.0f/(den + 1e-16f);
        uint32 pk = (uint32)f2bf(fmaxf(n0*rdn, 0.f)) | ((uint32)f2bf(fmaxf(n1*rdn, 0.f)) << 16);
        ((uint32*)o)[(size_t)d*64 + lane] = pk;
    }
}

// ---------------- semantic scores — MFMA 16x16x32 bf16
// block = 4 waves sharing one 16-node strip; wave w owns c-tiles {2w,2w+1}
__global__ __launch_bounds__(256) void score_mfma(
    const ushort16* __restrict__ o_em, const ushort16* __restrict__ o_mm,
    const float* __restrict__ Wk, const float* __restrict__ bkv,
    const float* __restrict__ qv, float* __restrict__ partials)
{
    int tid = threadIdx.x;
    int wv = tid >> 6, lane = tid & 63, quad = lane >> 4, sl = lane & 15;
    bf16x8 B[2][4];
    float bkc[2], qc[2];
    #pragma unroll
    for(int i=0;i<2;i++){
        int c = (2*wv+i)*16 + sl;
        const float* wr = Wk + c*HIDN;
        #pragma unroll
        for(int ks=0;ks<4;ks++) B[i][ks] = cvt8(wr + ks*32 + quad*8);
        bkc[i] = bkv[c]; qc[i] = qv[c];
    }
    float se = 0.f, sm = 0.f;
    for(int s = blockIdx.x; s < NSTRIPS; s += gridDim.x){
        int n0 = s*16;
        const bf16x8* rowE = (const bf16x8*)(o_em + (size_t)(n0+sl)*HIDN);
        const bf16x8* rowM = (const bf16x8*)(o_mm + (size_t)(n0+sl)*HIDN);
        bf16x8 AE[4], AM[4];
        #pragma unroll
        for(int ks=0;ks<4;ks++){
            AE[ks] = rowE[ks*4 + quad];     // 8 bf16 at k = ks*32 + quad*8
            AM[ks] = rowM[ks*4 + quad];
        }
        f32x4 aE[2], aM[2];
        #pragma unroll
        for(int i=0;i<2;i++){
            aE[i][0]=0.f;aE[i][1]=0.f;aE[i][2]=0.f;aE[i][3]=0.f;
            aM[i][0]=0.f;aM[i][1]=0.f;aM[i][2]=0.f;aM[i][3]=0.f;
        }
        #pragma unroll
        for(int i=0;i<2;i++)
            #pragma unroll
            for(int ks=0;ks<4;ks++){
                aE[i] = __builtin_amdgcn_mfma_f32_16x16x32_bf16(AE[ks], B[i][ks], aE[i], 0, 0, 0);
                aM[i] = __builtin_amdgcn_mfma_f32_16x16x32_bf16(AM[ks], B[i][ks], aM[i], 0, 0, 0);
            }
        #pragma unroll
        for(int i=0;i<2;i++)
            #pragma unroll
            for(int r=0;r<4;r++){
                se += qc[i]*tanhf(aE[i][r] + bkc[i]);
                sm += qc[i]*tanhf(aM[i][r] + bkc[i]);
            }
    }
    #pragma unroll
    for(int m=32;m>=1;m>>=1){ se += __shfl_xor(se,m); sm += __shfl_xor(sm,m); }
    __shared__ float red[8];
    if(lane==0){ red[wv*2]=se; red[wv*2+1]=sm; }
    __syncthreads();
    if(tid==0){
        partials[blockIdx.x*2+0] = red[0]+red[2]+red[4]+red[6];
        partials[blockIdx.x*2+1] = red[1]+red[3]+red[5]+red[7];
    }
}

__global__ __launch_bounds__(256) void reduce_scores_kernel(
    const float* __restrict__ partials, float* __restrict__ scores)
{
    __shared__ float sh0[256], sh1[256];
    int t = threadIdx.x;
    float s0=0.f, s1=0.f;
    for(int i=t;i<SCORE_BLOCKS;i+=256){ s0 += partials[2*i]; s1 += partials[2*i+1]; }
    sh0[t]=s0; sh1[t]=s1; __syncthreads();
    for(int s=128;s>0;s>>=1){ if(t<s){ sh0[t]+=sh0[t+s]; sh1[t]+=sh1[t+s]; } __syncthreads(); }
    if(t==0){ scores[0]=sh0[0]; scores[1]=sh1[0]; }
}

// ---------------- final — LDS-tiled (unchanged from r7)
__global__ __launch_bounds__(128) void final_v3(
    const ushort16* __restrict__ o_em, const ushort16* __restrict__ o_mm,
    const float* __restrict__ Wl, const float* __restrict__ blv,
    const float* __restrict__ scores, float* __restrict__ out)
{
    __shared__ float wlds[64*129];
    __shared__ float zlds[NT*128];
    int t = threadIdx.x;
    #pragma unroll 2
    for(int i=t;i<2048;i+=128){
        float4 v = ((const float4*)Wl)[i];
        int r = i >> 5, k4 = i & 31;
        float* d = wlds + r*129 + k4*4;
        d[0]=v.x; d[1]=v.y; d[2]=v.z; d[3]=v.w;
    }
    float s0 = scores[0]*(1.0f/N_MATN), s1 = scores[1]*(1.0f/N_MATN);
    float mx = fmaxf(s0,s1);
    float e0 = __expf(s0-mx), e1 = __expf(s1-mx);
    float inv = 1.0f/(e0+e1);
    float a0 = e0*inv, a1 = e1*inv;
    int j = t & 63, half = t >> 6;
    float bj = blv[j];
    const float* wr = wlds + j*129;
    __syncthreads();
    for(int tile = blockIdx.x; tile < NTILES; tile += gridDim.x){
        int n0 = tile*NT;
        __syncthreads();
        {
            const uint4* pe = (const uint4*)((const uint32*)o_em + (size_t)n0*64);
            const uint4* pm = (const uint4*)((const uint32*)o_mm + (size_t)n0*64);
            uint4 ve = pe[t], vm = pm[t];
            float* zd = zlds + t*8;
            zd[0]=a0*blo(ve.x)+a1*blo(vm.x); zd[1]=a0*bhi(ve.x)+a1*bhi(vm.x);
            zd[2]=a0*blo(ve.y)+a1*blo(vm.y); zd[3]=a0*bhi(ve.y)+a1*bhi(vm.y);
            zd[4]=a0*blo(ve.z)+a1*blo(vm.z); zd[5]=a0*bhi(ve.z)+a1*bhi(vm.z);
            zd[6]=a0*blo(ve.w)+a1*blo(vm.w); zd[7]=a0*bhi(ve.w)+a1*bhi(vm.w);
        }
        __syncthreads();
        float acc[4] = {0.f,0.f,0.f,0.f};
        #pragma unroll 1
        for(int kk=0;kk<128;kk+=8){
            float f0=wr[kk],f1=wr[kk+1],f2=wr[kk+2],f3=wr[kk+3];
            float f4=wr[kk+4],f5=wr[kk+5],f6=wr[kk+6],f7=wr[kk+7];
            #pragma unroll
            for(int n=0;n<4;n++){
                const float4* zr = (const float4*)(zlds + (half*4+n)*128 + kk);
                float4 za = zr[0], zb = zr[1];
                acc[n] += za.x*f0 + za.y*f1 + za.z*f2 + za.w*f3
                        + zb.x*f4 + zb.y*f5 + zb.z*f6 + zb.w*f7;
            }
        }
        #pragma unroll
        for(int n=0;n<4;n++)
            out[(size_t)(n0 + half*4 + n)*OUTC + j] = bj + acc[n];
    }
}

extern "C" void kernel_launch(void* const* d_in, const int* in_sizes, int n_in,
                              void* d_out, int out_size, void* d_ws, size_t ws_size,
                              hipStream_t stream)
{
    const float* x_mat    = (const float*)d_in[0];
    const float* x_elem   = (const float*)d_in[1];
    const float* W_pm     = (const float*)d_in[2];
    const float* b_pm     = (const float*)d_in[3];
    const float* W_pe     = (const float*)d_in[4];
    const float* b_pe     = (const float*)d_in[5];
    const float* a_se     = (const float*)d_in[6];
    const float* a_de     = (const float*)d_in[7];
    const float* a_sm     = (const float*)d_in[8];
    const float* a_dm     = (const float*)d_in[9];
    const float* Wk       = (const float*)d_in[10];
    const float* bk       = (const float*)d_in[11];
    const float* qv       = (const float*)d_in[12];
    const float* Wl       = (const float*)d_in[13];
    const float* bl       = (const float*)d_in[14];
    const int* src_em     = (const int*)d_in[15];
    const int* dst_em     = (const int*)d_in[16];
    const int* src_mm     = (const int*)d_in[17];
    const int* dst_mm     = (const int*)d_in[18];
    int nE_em = in_sizes[15];
    int nE_mm = in_sizes[17];

    char* ws = (char*)d_ws;
    size_t off = 0;
    auto alloc = [&](size_t bytes) -> void* {
        void* p = ws + off; off += (bytes + 255) & ~size_t(255); return p;
    };
    ushort16* h_mat   = (ushort16*)alloc((size_t)N_MATN*HIDN*2);
    ushort16* h_elem  = (ushort16*)alloc((size_t)N_ELEMN*HIDN*2);
    float*    asrcEM  = (float*)   alloc((size_t)N_ELEMN*NHEAD*4);
    float*    adstEM  = (float*)   alloc((size_t)N_MATN*NHEAD*4);
    float*    asrcMM  = (float*)   alloc((size_t)N_MATN*NHEAD*4);
    float*    adstMM  = (float*)   alloc((size_t)N_MATN*NHEAD*4);
    int*      offs_em = (int*)     alloc((size_t)(N_MATN+1)*4);
    int*      offs_mm = (int*)     alloc((size_t)(N_MATN+1)*4);
    int*      csr_em  = (int*)     alloc((size_t)1000000*4);
    int*      csr_mm  = (int*)     alloc((size_t)2000000*4);
    ushort16* o_em    = (ushort16*)alloc((size_t)N_MATN*HIDN*2);
    ushort16* o_mm    = (ushort16*)alloc((size_t)N_MATN*HIDN*2);
    float*    partials= (float*)   alloc((size_t)SCORE_BLOCKS*2*4);
    float*    scores  = (float*)   alloc(256);
    size_t zero_start = off;
    int*      deg_em  = (int*)     alloc((size_t)N_MATN*4);
    int*      deg_mm  = (int*)     alloc((size_t)N_MATN*4);
    size_t zero_bytes = off - zero_start;

    hipMemsetAsync(ws + zero_start, 0, zero_bytes, stream);

    proj_elem_v2<<<N_ELEMN, 128, 0, stream>>>(x_elem, W_pe, b_pe, a_se, h_elem, asrcEM);
    proj_mat_mfma<<<1024, 256, 0, stream>>>(x_mat, W_pm, b_pm, a_de, a_sm, a_dm,
                                            h_mat, adstEM, asrcMM, adstMM);

    count_kernel<<<1024, 256, 0, stream>>>(dst_em, nE_em, deg_em);
    count_kernel<<<1024, 256, 0, stream>>>(dst_mm, nE_mm, deg_mm);
    scan_kernel<<<1, 256, 0, stream>>>(deg_em, offs_em);
    scan_kernel<<<1, 256, 0, stream>>>(deg_mm, offs_mm);
    copy_kernel<<<256, 256, 0, stream>>>(offs_em, deg_em, N_MATN);
    copy_kernel<<<256, 256, 0, stream>>>(offs_mm, deg_mm, N_MATN);
    scatter_kernel<<<1024, 256, 0, stream>>>(src_em, dst_em, nE_em, deg_em, csr_em);
    scatter_kernel<<<1024, 256, 0, stream>>>(src_mm, dst_mm, nE_mm, deg_mm, csr_mm);

    agg_kernel<<<2048, 256, 0, stream>>>(offs_em, csr_em, h_elem, asrcEM, adstEM, o_em);
    agg_kernel<<<2048, 256, 0, stream>>>(offs_mm, csr_mm, h_mat, asrcMM, adstMM, o_mm);

    score_mfma<<<SCORE_BLOCKS, 256, 0, stream>>>(o_em, o_mm, Wk, bk, qv, partials);
    reduce_scores_kernel<<<1, 256, 0, stream>>>(partials, scores);
    final_v3<<<1024, 128, 0, stream>>>(o_em, o_mm, Wl, bl, scores, (float*)d_out);
}

// Round 9
// 1046.635 us; speedup vs baseline: 3.7282x; 1.1846x over previous
//
#include <hip/hip_runtime.h>
#include <hip/hip_bf16.h>

typedef unsigned int uint32;
typedef unsigned short ushort16;

using bf16x8 = __attribute__((ext_vector_type(8))) short;
using f32x4  = __attribute__((ext_vector_type(4))) float;

#define N_MATN 100000
#define N_ELEMN 118
#define F_MATN 128
#define F_ELEMN 64
#define HIDN 128
#define NHEAD 8
#define OUTC 64
#define SCORE_BLOCKS 1024
#define NSTRIPS 6250              // 100000 / 16
#define NT 8
#define NTILES (N_MATN/NT)

__device__ __forceinline__ float blo(uint32 u){ return __uint_as_float(u << 16); }
__device__ __forceinline__ float bhi(uint32 u){ return __uint_as_float(u & 0xffff0000u); }
__device__ __forceinline__ ushort16 f2bf(float f){
    uint32 u = __float_as_uint(f);
    uint32 r = u + 0x7FFFu + ((u >> 16) & 1u);   // RNE
    return (ushort16)(r >> 16);
}
__device__ __forceinline__ bf16x8 cvt8(const float* __restrict__ p){
    bf16x8 r;
    #pragma unroll
    for(int j=0;j<8;j++) r[j] = (short)f2bf(p[j]);
    return r;
}

// ---------------- projection: elem nodes — one block per node (unchanged)
__global__ __launch_bounds__(128) void proj_elem_v2(
    const float* __restrict__ x, const float* __restrict__ W,
    const float* __restrict__ bias, const float* __restrict__ a_se,
    ushort16* __restrict__ h, float* __restrict__ asrc_em)
{
    __shared__ float xr[F_ELEMN];
    int n = blockIdx.x, c = threadIdx.x;
    if(c < 16) ((float4*)xr)[c] = ((const float4*)(x + n*F_ELEMN))[c];
    __syncthreads();
    const float4* Wr = (const float4*)(W + c*F_ELEMN);
    float acc = 0.f;
    #pragma unroll 4
    for(int i=0;i<16;i++){
        float4 w = Wr[i];
        acc += xr[4*i]*w.x + xr[4*i+1]*w.y + xr[4*i+2]*w.z + xr[4*i+3]*w.w;
    }
    acc += bias[c];
    h[n*HIDN + c] = f2bf(acc);
    float p = acc * a_se[c];
    #pragma unroll
    for(int m=8;m>=1;m>>=1) p += __shfl_xor(p, m, 16);
    if((c&15)==0) asrc_em[n*NHEAD + (c>>4)] = p;
}

// ---------------- projection: mat nodes — MFMA 16x16x32 bf16 (unchanged)
__global__ __launch_bounds__(256) void proj_mat_mfma(
    const float* __restrict__ x, const float* __restrict__ W,
    const float* __restrict__ bias,
    const float* __restrict__ a_de, const float* __restrict__ a_sm, const float* __restrict__ a_dm,
    ushort16* __restrict__ h,
    float* __restrict__ adst_em, float* __restrict__ asrc_mm, float* __restrict__ adst_mm)
{
    int tid = threadIdx.x;
    int wv = tid >> 6, lane = tid & 63, quad = lane >> 4, sl = lane & 15;
    bf16x8 B[2][4];
    float bc[2], ade[2], asv[2], adv[2];
    #pragma unroll
    for(int i=0;i<2;i++){
        int c = (2*wv+i)*16 + sl;
        const float* wr = W + c*F_MATN;
        #pragma unroll
        for(int ks=0;ks<4;ks++) B[i][ks] = cvt8(wr + ks*32 + quad*8);
        bc[i] = bias[c]; ade[i] = a_de[c]; asv[i] = a_sm[c]; adv[i] = a_dm[c];
    }
    for(int s = blockIdx.x; s < NSTRIPS; s += gridDim.x){
        int n0 = s*16;
        const float* xrow = x + (size_t)(n0+sl)*F_MATN;
        bf16x8 A[4];
        #pragma unroll
        for(int ks=0;ks<4;ks++) A[ks] = cvt8(xrow + ks*32 + quad*8);
        f32x4 acc[2];
        #pragma unroll
        for(int i=0;i<2;i++){ acc[i][0]=0.f; acc[i][1]=0.f; acc[i][2]=0.f; acc[i][3]=0.f; }
        #pragma unroll
        for(int i=0;i<2;i++)
            #pragma unroll
            for(int ks=0;ks<4;ks++)
                acc[i] = __builtin_amdgcn_mfma_f32_16x16x32_bf16(A[ks], B[i][ks], acc[i], 0, 0, 0);
        #pragma unroll
        for(int i=0;i<2;i++){
            int head = 2*wv + i;
            #pragma unroll
            for(int r=0;r<4;r++){
                float a = acc[i][r] + bc[i];
                int node = n0 + quad*4 + r;
                h[(size_t)node*HIDN + head*16 + sl] = f2bf(a);
                float p0 = a*ade[i], p1 = a*asv[i], p2 = a*adv[i];
                #pragma unroll
                for(int m=8;m>=1;m>>=1){
                    p0 += __shfl_xor(p0, m);
                    p1 += __shfl_xor(p1, m);
                    p2 += __shfl_xor(p2, m);
                }
                if(sl == 0){
                    adst_em[node*NHEAD + head] = p0;
                    asrc_mm[node*NHEAD + head] = p1;
                    adst_mm[node*NHEAD + head] = p2;
                }
            }
        }
    }
}

// ---------------- CSR build: fused count (both edge types)
__global__ __launch_bounds__(256) void count_both(
    const int* __restrict__ dst_em, int nE_em, int* __restrict__ deg_em,
    const int* __restrict__ dst_mm, int nE_mm, int* __restrict__ deg_mm)
{
    int i = blockIdx.x*blockDim.x + threadIdx.x;
    int st = gridDim.x*blockDim.x;
    int tot = nE_em + nE_mm;
    for(; i < tot; i += st){
        if(i < nE_em) atomicAdd(&deg_em[dst_em[i]], 1);
        else          atomicAdd(&deg_mm[dst_mm[i - nE_em]], 1);
    }
}

// ---------------- CSR build: fused scan (block 0 = em, block 1 = mm);
// writes offs[] and converts deg[] in-place to the scatter cursor
__global__ __launch_bounds__(256) void scan_both(
    int* __restrict__ deg_em, int* __restrict__ offs_em,
    int* __restrict__ deg_mm, int* __restrict__ offs_mm)
{
    int* deg  = blockIdx.x ? deg_mm  : deg_em;
    int* offs = blockIdx.x ? offs_mm : offs_em;
    __shared__ int part[256];
    int t = threadIdx.x;
    const int CH = (N_MATN + 255) >> 8;
    int beg = t*CH;
    int end = beg + CH; if(end > N_MATN) end = N_MATN;
    int s = 0;
    for(int i = beg; i < end; i++) s += deg[i];
    part[t] = s;
    __syncthreads();
    if(t == 0){
        int run = 0;
        for(int i = 0; i < 256; i++){ int v = part[i]; part[i] = run; run += v; }
    }
    __syncthreads();
    int run = part[t];
    for(int i = beg; i < end; i++){
        int v = deg[i];
        offs[i] = run;
        deg[i] = run;        // cursor for scatter
        run += v;
    }
    if(t == 255) offs[N_MATN] = run;
}

// ---------------- CSR build: fused scatter
__global__ __launch_bounds__(256) void scatter_both(
    const int* __restrict__ src_em, const int* __restrict__ dst_em, int nE_em,
    int* __restrict__ cur_em, int* __restrict__ csr_em,
    const int* __restrict__ src_mm, const int* __restrict__ dst_mm, int nE_mm,
    int* __restrict__ cur_mm, int* __restrict__ csr_mm)
{
    int i = blockIdx.x*blockDim.x + threadIdx.x;
    int st = gridDim.x*blockDim.x;
    int tot = nE_em + nE_mm;
    for(; i < tot; i += st){
        if(i < nE_em){
            int d = dst_em[i];
            int p = atomicAdd(&cur_em[d], 1);
            csr_em[p] = src_em[i];
        } else {
            int k = i - nE_em;
            int d = dst_mm[k];
            int p = atomicAdd(&cur_mm[d], 1);
            csr_mm[p] = src_mm[k];
        }
    }
}

// ---------------- aggregation: fused em+mm, one wave per dst node, 4x-unrolled MLP
__global__ __launch_bounds__(256) void agg_both(
    const int* __restrict__ offs_em, const int* __restrict__ csr_em,
    const ushort16* __restrict__ h_elem, const float* __restrict__ asrc_em,
    const float* __restrict__ adst_em, ushort16* __restrict__ o_em,
    const int* __restrict__ offs_mm, const int* __restrict__ csr_mm,
    const ushort16* __restrict__ h_mat, const float* __restrict__ asrc_mm,
    const float* __restrict__ adst_mm, ushort16* __restrict__ o_mm)
{
    int lane = threadIdx.x & 63;
    int w = (blockIdx.x*blockDim.x + threadIdx.x) >> 6;
    int nw = (gridDim.x*blockDim.x) >> 6;
    int hh = lane >> 3;
    for(int nid = w; nid < 2*N_MATN; nid += nw){
        bool em = nid < N_MATN;
        int d = em ? nid : nid - N_MATN;
        const int*    offs = em ? offs_em : offs_mm;
        const int*    csr  = em ? csr_em  : csr_mm;
        const uint32* hs   = (const uint32*)(em ? h_elem : h_mat);
        const float*  asp  = em ? asrc_em : asrc_mm;
        const float*  adp  = em ? adst_em : adst_mm;
        uint32*       op   = (uint32*)(em ? o_em : o_mm);
        int beg = offs[d], end = offs[d+1];
        float ad = adp[d*NHEAD + hh];
        float den = 0.f, n0 = 0.f, n1 = 0.f;
        int j = beg;
        for(; j + 4 <= end; j += 4){
            int s0 = csr[j], s1 = csr[j+1], s2 = csr[j+2], s3 = csr[j+3];
            float a0 = asp[s0*NHEAD+hh], a1 = asp[s1*NHEAD+hh];
            float a2 = asp[s2*NHEAD+hh], a3 = asp[s3*NHEAD+hh];
            uint32 h0 = hs[(size_t)s0*64 + lane];
            uint32 h1 = hs[(size_t)s1*64 + lane];
            uint32 h2 = hs[(size_t)s2*64 + lane];
            uint32 h3 = hs[(size_t)s3*64 + lane];
            float al, ex;
            al = a0 + ad; al = al > 0.f ? al : 0.2f*al; ex = __expf(al);
            den += ex; n0 += blo(h0)*ex; n1 += bhi(h0)*ex;
            al = a1 + ad; al = al > 0.f ? al : 0.2f*al; ex = __expf(al);
            den += ex; n0 += blo(h1)*ex; n1 += bhi(h1)*ex;
            al = a2 + ad; al = al > 0.f ? al : 0.2f*al; ex = __expf(al);
            den += ex; n0 += blo(h2)*ex; n1 += bhi(h2)*ex;
            al = a3 + ad; al = al > 0.f ? al : 0.2f*al; ex = __expf(al);
            den += ex; n0 += blo(h3)*ex; n1 += bhi(h3)*ex;
        }
        for(; j < end; j++){
            int s = csr[j];
            float al = asp[s*NHEAD + hh] + ad;
            al = al > 0.f ? al : 0.2f*al;
            float ex = __expf(al);
            den += ex;
            uint32 hv = hs[(size_t)s*64 + lane];
            n0 += blo(hv)*ex;
            n1 += bhi(hv)*ex;
        }
        float rdn = 1.0f/(den + 1e-16f);
        uint32 pk = (uint32)f2bf(fmaxf(n0*rdn, 0.f)) | ((uint32)f2bf(fmaxf(n1*rdn, 0.f)) << 16);
        op[(size_t)d*64 + lane] = pk;
    }
}

// ---------------- semantic scores — MFMA (unchanged)
__global__ __launch_bounds__(256) void score_mfma(
    const ushort16* __restrict__ o_em, const ushort16* __restrict__ o_mm,
    const float* __restrict__ Wk, const float* __restrict__ bkv,
    const float* __restrict__ qv, float* __restrict__ partials)
{
    int tid = threadIdx.x;
    int wv = tid >> 6, lane = tid & 63, quad = lane >> 4, sl = lane & 15;
    bf16x8 B[2][4];
    float bkc[2], qc[2];
    #pragma unroll
    for(int i=0;i<2;i++){
        int c = (2*wv+i)*16 + sl;
        const float* wr = Wk + c*HIDN;
        #pragma unroll
        for(int ks=0;ks<4;ks++) B[i][ks] = cvt8(wr + ks*32 + quad*8);
        bkc[i] = bkv[c]; qc[i] = qv[c];
    }
    float se = 0.f, sm = 0.f;
    for(int s = blockIdx.x; s < NSTRIPS; s += gridDim.x){
        int n0 = s*16;
        const bf16x8* rowE = (const bf16x8*)(o_em + (size_t)(n0+sl)*HIDN);
        const bf16x8* rowM = (const bf16x8*)(o_mm + (size_t)(n0+sl)*HIDN);
        bf16x8 AE[4], AM[4];
        #pragma unroll
        for(int ks=0;ks<4;ks++){
            AE[ks] = rowE[ks*4 + quad];
            AM[ks] = rowM[ks*4 + quad];
        }
        f32x4 aE[2], aM[2];
        #pragma unroll
        for(int i=0;i<2;i++){
            aE[i][0]=0.f;aE[i][1]=0.f;aE[i][2]=0.f;aE[i][3]=0.f;
            aM[i][0]=0.f;aM[i][1]=0.f;aM[i][2]=0.f;aM[i][3]=0.f;
        }
        #pragma unroll
        for(int i=0;i<2;i++)
            #pragma unroll
            for(int ks=0;ks<4;ks++){
                aE[i] = __builtin_amdgcn_mfma_f32_16x16x32_bf16(AE[ks], B[i][ks], aE[i], 0, 0, 0);
                aM[i] = __builtin_amdgcn_mfma_f32_16x16x32_bf16(AM[ks], B[i][ks], aM[i], 0, 0, 0);
            }
        #pragma unroll
        for(int i=0;i<2;i++)
            #pragma unroll
            for(int r=0;r<4;r++){
                se += qc[i]*tanhf(aE[i][r] + bkc[i]);
                sm += qc[i]*tanhf(aM[i][r] + bkc[i]);
            }
    }
    #pragma unroll
    for(int m=32;m>=1;m>>=1){ se += __shfl_xor(se,m); sm += __shfl_xor(sm,m); }
    __shared__ float red[8];
    if(lane==0){ red[wv*2]=se; red[wv*2+1]=sm; }
    __syncthreads();
    if(tid==0){
        partials[blockIdx.x*2+0] = red[0]+red[2]+red[4]+red[6];
        partials[blockIdx.x*2+1] = red[1]+red[3]+red[5]+red[7];
    }
}

__global__ __launch_bounds__(256) void reduce_scores_kernel(
    const float* __restrict__ partials, float* __restrict__ scores)
{
    __shared__ float sh0[256], sh1[256];
    int t = threadIdx.x;
    float s0=0.f, s1=0.f;
    for(int i=t;i<SCORE_BLOCKS;i+=256){ s0 += partials[2*i]; s1 += partials[2*i+1]; }
    sh0[t]=s0; sh1[t]=s1; __syncthreads();
    for(int s=128;s>0;s>>=1){ if(t<s){ sh0[t]+=sh0[t+s]; sh1[t]+=sh1[t+s]; } __syncthreads(); }
    if(t==0){ scores[0]=sh0[0]; scores[1]=sh1[0]; }
}

// ---------------- final — LDS-tiled (unchanged)
__global__ __launch_bounds__(128) void final_v3(
    const ushort16* __restrict__ o_em, const ushort16* __restrict__ o_mm,
    const float* __restrict__ Wl, const float* __restrict__ blv,
    const float* __restrict__ scores, float* __restrict__ out)
{
    __shared__ float wlds[64*129];
    __shared__ float zlds[NT*128];
    int t = threadIdx.x;
    #pragma unroll 2
    for(int i=t;i<2048;i+=128){
        float4 v = ((const float4*)Wl)[i];
        int r = i >> 5, k4 = i & 31;
        float* d = wlds + r*129 + k4*4;
        d[0]=v.x; d[1]=v.y; d[2]=v.z; d[3]=v.w;
    }
    float s0 = scores[0]*(1.0f/N_MATN), s1 = scores[1]*(1.0f/N_MATN);
    float mx = fmaxf(s0,s1);
    float e0 = __expf(s0-mx), e1 = __expf(s1-mx);
    float inv = 1.0f/(e0+e1);
    float a0 = e0*inv, a1 = e1*inv;
    int j = t & 63, half = t >> 6;
    float bj = blv[j];
    const float* wr = wlds + j*129;
    __syncthreads();
    for(int tile = blockIdx.x; tile < NTILES; tile += gridDim.x){
        int n0 = tile*NT;
        __syncthreads();
        {
            const uint4* pe = (const uint4*)((const uint32*)o_em + (size_t)n0*64);
            const uint4* pm = (const uint4*)((const uint32*)o_mm + (size_t)n0*64);
            uint4 ve = pe[t], vm = pm[t];
            float* zd = zlds + t*8;
            zd[0]=a0*blo(ve.x)+a1*blo(vm.x); zd[1]=a0*bhi(ve.x)+a1*bhi(vm.x);
            zd[2]=a0*blo(ve.y)+a1*blo(vm.y); zd[3]=a0*bhi(ve.y)+a1*bhi(vm.y);
            zd[4]=a0*blo(ve.z)+a1*blo(vm.z); zd[5]=a0*bhi(ve.z)+a1*bhi(vm.z);
            zd[6]=a0*blo(ve.w)+a1*blo(vm.w); zd[7]=a0*bhi(ve.w)+a1*bhi(vm.w);
        }
        __syncthreads();
        float acc[4] = {0.f,0.f,0.f,0.f};
        #pragma unroll 1
        for(int kk=0;kk<128;kk+=8){
            float f0=wr[kk],f1=wr[kk+1],f2=wr[kk+2],f3=wr[kk+3];
            float f4=wr[kk+4],f5=wr[kk+5],f6=wr[kk+6],f7=wr[kk+7];
            #pragma unroll
            for(int n=0;n<4;n++){
                const float4* zr = (const float4*)(zlds + (half*4+n)*128 + kk);
                float4 za = zr[0], zb = zr[1];
                acc[n] += za.x*f0 + za.y*f1 + za.z*f2 + za.w*f3
                        + zb.x*f4 + zb.y*f5 + zb.z*f6 + zb.w*f7;
            }
        }
        #pragma unroll
        for(int n=0;n<4;n++)
            out[(size_t)(n0 + half*4 + n)*OUTC + j] = bj + acc[n];
    }
}

extern "C" void kernel_launch(void* const* d_in, const int* in_sizes, int n_in,
                              void* d_out, int out_size, void* d_ws, size_t ws_size,
                              hipStream_t stream)
{
    const float* x_mat    = (const float*)d_in[0];
    const float* x_elem   = (const float*)d_in[1];
    const float* W_pm     = (const float*)d_in[2];
    const float* b_pm     = (const float*)d_in[3];
    const float* W_pe     = (const float*)d_in[4];
    const float* b_pe     = (const float*)d_in[5];
    const float* a_se     = (const float*)d_in[6];
    const float* a_de     = (const float*)d_in[7];
    const float* a_sm     = (const float*)d_in[8];
    const float* a_dm     = (const float*)d_in[9];
    const float* Wk       = (const float*)d_in[10];
    const float* bk       = (const float*)d_in[11];
    const float* qv       = (const float*)d_in[12];
    const float* Wl       = (const float*)d_in[13];
    const float* bl       = (const float*)d_in[14];
    const int* src_em     = (const int*)d_in[15];
    const int* dst_em     = (const int*)d_in[16];
    const int* src_mm     = (const int*)d_in[17];
    const int* dst_mm     = (const int*)d_in[18];
    int nE_em = in_sizes[15];
    int nE_mm = in_sizes[17];

    char* ws = (char*)d_ws;
    size_t off = 0;
    auto alloc = [&](size_t bytes) -> void* {
        void* p = ws + off; off += (bytes + 255) & ~size_t(255); return p;
    };
    ushort16* h_mat   = (ushort16*)alloc((size_t)N_MATN*HIDN*2);
    ushort16* h_elem  = (ushort16*)alloc((size_t)N_ELEMN*HIDN*2);
    float*    asrcEM  = (float*)   alloc((size_t)N_ELEMN*NHEAD*4);
    float*    adstEM  = (float*)   alloc((size_t)N_MATN*NHEAD*4);
    float*    asrcMM  = (float*)   alloc((size_t)N_MATN*NHEAD*4);
    float*    adstMM  = (float*)   alloc((size_t)N_MATN*NHEAD*4);
    int*      offs_em = (int*)     alloc((size_t)(N_MATN+1)*4);
    int*      offs_mm = (int*)     alloc((size_t)(N_MATN+1)*4);
    int*      csr_em  = (int*)     alloc((size_t)1000000*4);
    int*      csr_mm  = (int*)     alloc((size_t)2000000*4);
    ushort16* o_em    = (ushort16*)alloc((size_t)N_MATN*HIDN*2);
    ushort16* o_mm    = (ushort16*)alloc((size_t)N_MATN*HIDN*2);
    float*    partials= (float*)   alloc((size_t)SCORE_BLOCKS*2*4);
    float*    scores  = (float*)   alloc(256);
    size_t zero_start = off;
    int*      deg_em  = (int*)     alloc((size_t)N_MATN*4);   // becomes scatter cursor after scan
    int*      deg_mm  = (int*)     alloc((size_t)N_MATN*4);
    size_t zero_bytes = off - zero_start;

    hipMemsetAsync(ws + zero_start, 0, zero_bytes, stream);

    proj_elem_v2<<<N_ELEMN, 128, 0, stream>>>(x_elem, W_pe, b_pe, a_se, h_elem, asrcEM);
    proj_mat_mfma<<<1024, 256, 0, stream>>>(x_mat, W_pm, b_pm, a_de, a_sm, a_dm,
                                            h_mat, adstEM, asrcMM, adstMM);

    count_both<<<2048, 256, 0, stream>>>(dst_em, nE_em, deg_em, dst_mm, nE_mm, deg_mm);
    scan_both<<<2, 256, 0, stream>>>(deg_em, offs_em, deg_mm, offs_mm);
    scatter_both<<<2048, 256, 0, stream>>>(src_em, dst_em, nE_em, deg_em, csr_em,
                                           src_mm, dst_mm, nE_mm, deg_mm, csr_mm);

    agg_both<<<4096, 256, 0, stream>>>(offs_em, csr_em, h_elem, asrcEM, adstEM, o_em,
                                       offs_mm, csr_mm, h_mat, asrcMM, adstMM, o_mm);

    score_mfma<<<SCORE_BLOCKS, 256, 0, stream>>>(o_em, o_mm, Wk, bk, qv, partials);
    reduce_scores_kernel<<<1, 256, 0, stream>>>(partials, scores);
    final_v3<<<1024, 128, 0, stream>>>(o_em, o_mm, Wl, bl, scores, (float*)d_out);
}